// Round 12
// baseline (440.975 us; speedup 1.0000x reference)
//
#include <hip/hip_runtime.h>

// ---------------------------------------------------------------------------
// CausalSelfAttention2: x@Wqkv -> rope -> 512x block-causal attn -> o@Wo ;
// plus learned time-pooled qb/kb/vb outputs.
// Sizes: B=4 T=4096 C=1024 H=16 G=8 HS=64 GT=512. d_out is FLOAT32.
// R18: gemm1 LDS union — Es (epilogue restage, 17.4KB) now ALIASES As/Bs
// (32KB), guarded by one __syncthreads after gemm_core (all K-loop ds_reads
// complete). LDS_Block 50.2KB -> 32.8KB => 4 blocks/CU (16 waves, was ~2/8).
// R17 counters showed gemm1 Occupancy 20.5% / MfmaUtil 26.5%: the vmcnt(0)
// barrier drain has no co-resident MFMA work to hide under; doubling
// resident blocks supplies it (m114 implicit-overlap mechanism).
// R16 XCD swizzles, R15 BK=64 core, R13/R14 attn, pools unchanged.
// ---------------------------------------------------------------------------

typedef float  float4_t  __attribute__((ext_vector_type(4)));
typedef short  bfrag     __attribute__((ext_vector_type(8)));   // 8 bf16
typedef unsigned short ushort8 __attribute__((ext_vector_type(8)));

#define MFMA_BF16(A, B, C) __builtin_amdgcn_mfma_f32_16x16x32_bf16((A), (B), (C), 0, 0, 0)

__device__ __forceinline__ unsigned short f2bf(float f) {
  union { float f; unsigned u; } v; v.f = f;
  return (unsigned short)((v.u + 0x7FFFu + ((v.u >> 16) & 1u)) >> 16);   // RNE
}
__device__ __forceinline__ float bf2f(unsigned short h) {
  union { unsigned u; float f; } v; v.u = ((unsigned)h) << 16; return v.f;
}
// async global->LDS, 16B per lane; LDS dest = wave-uniform base + lane*16
__device__ __forceinline__ void async16(const void* g, void* l) {
  __builtin_amdgcn_global_load_lds(
      (const __attribute__((address_space(1))) unsigned int*)(unsigned long long)g,
      (__attribute__((address_space(3))) unsigned int*)(unsigned long long)l,
      16, 0, 0);
}

// ---------------------------------------------------------------------------
// f32 -> bf16 convert (8 elems/thread)
__global__ __launch_bounds__(256) void cvt_kernel(const float* __restrict__ in,
                                                  unsigned short* __restrict__ out, int n8) {
  int i = blockIdx.x * 256 + threadIdx.x;
  if (i >= n8) return;
  const float4_t* p = (const float4_t*)in + (size_t)i * 2;
  float4_t a = p[0], c = p[1];
  ushort8 r;
  r[0] = f2bf(a[0]); r[1] = f2bf(a[1]); r[2] = f2bf(a[2]); r[3] = f2bf(a[3]);
  r[4] = f2bf(c[0]); r[5] = f2bf(c[1]); r[6] = f2bf(c[2]); r[7] = f2bf(c[3]);
  *((ushort8*)out + i) = r;
}

// out[n][k] = bf16(in[k][n]);  in is [R,C] f32, out is [C,R] bf16
__global__ void transpose_cvt_kernel(const float* __restrict__ in,
                                     unsigned short* __restrict__ out, int R, int C) {
  __shared__ float t[32][33];
  int bc = blockIdx.x * 32, br = blockIdx.y * 32;
  int x = threadIdx.x, y = threadIdx.y;
  for (int i = 0; i < 32; i += 8) t[y + i][x] = in[(size_t)(br + y + i) * C + bc + x];
  __syncthreads();
  for (int i = 0; i < 32; i += 8) out[(size_t)(bc + y + i) * R + br + x] = f2bf(t[x][y + i]);
}

// out[n][k] = in[k][n]; f32 transpose of TWO tables (z selects), R=4096 C=32
__global__ void transpose2_f32_kernel(const float* __restrict__ a,
                                      const float* __restrict__ b,
                                      float* __restrict__ oa, float* __restrict__ ob_,
                                      int R, int C) {
  const float* in = blockIdx.z ? b : a;
  float* out = blockIdx.z ? ob_ : oa;
  __shared__ float t[32][33];
  int bc = blockIdx.x * 32, br = blockIdx.y * 32;
  int x = threadIdx.x, y = threadIdx.y;
  for (int i = 0; i < 32; i += 8) t[y + i][x] = in[(size_t)(br + y + i) * C + bc + x];
  __syncthreads();
  for (int i = 0; i < 32; i += 8) out[(size_t)(bc + y + i) * R + br + x] = t[x][y + i];
}

// ---------------------------------------------------------------------------
// Shared GEMM core: C128x128 tile, BK=64, 4 waves (each 64x64 = 4x4 mfma frags)
// A [M,K] bf16 row-major, BT [N,K] bf16 row-major.
// LDS tile 128x64: slot s (16B) holds row s>>3, chunk (s&7)^((s>>3)&7).
__device__ __forceinline__ void gemm_core(const unsigned short* __restrict__ A,
                                          const unsigned short* __restrict__ BT,
                                          int bm0, int bn0, int K,
                                          unsigned short* As, unsigned short* Bs,
                                          float4_t acc[4][4]) {
  int tid = threadIdx.x, w = tid >> 6;
  int lane = tid & 63, quad = lane >> 4, l16 = lane & 15;
  int wm = w >> 1, wn = w & 1;
  int r = tid >> 3, x = tid & 7;
  int sc = (x ^ (r & 7)) * 8;                      // swizzled source col
  for (int k0 = 0; k0 < K; k0 += 64) {
    __syncthreads();
#pragma unroll
    for (int c = 0; c < 4; ++c) {
      async16(&A [(size_t)(bm0 + c * 32 + r) * K + k0 + sc], &As[(size_t)(c * 256 + w * 64) * 8]);
      async16(&BT[(size_t)(bn0 + c * 32 + r) * K + k0 + sc], &Bs[(size_t)(c * 256 + w * 64) * 8]);
    }
    __syncthreads();
#pragma unroll
    for (int ks = 0; ks < 2; ++ks) {
      bfrag af[4], bf_[4];
#pragma unroll
      for (int i = 0; i < 4; ++i) {
        int rm = wm * 64 + i * 16 + l16;
        af[i]  = *(const bfrag*)&As[(size_t)(rm * 8 + ((ks * 4 + quad) ^ (rm & 7))) * 8];
        int rn = wn * 64 + i * 16 + l16;
        bf_[i] = *(const bfrag*)&Bs[(size_t)(rn * 8 + ((ks * 4 + quad) ^ (rn & 7))) * 8];
      }
#pragma unroll
      for (int i = 0; i < 4; ++i)
#pragma unroll
        for (int j = 0; j < 4; ++j)
          acc[i][j] = MFMA_BF16(af[i], bf_[j], acc[i][j]);
    }
  }
}

// GEMM1: qkv = rope(x @ Wqkv) stored PLAIN row-major [16384][3072].
// R18: Es aliased onto As/Bs (epilogue-only use, guarded by a barrier) ->
// LDS 32.8KB -> 4 blocks/CU. R16 XCD swizzle retained.
__global__ __launch_bounds__(256) void gemm1_kernel(const unsigned short* __restrict__ xb,
    const unsigned short* __restrict__ wqkvT,
    const float* __restrict__ fcT, const float* __restrict__ fsT,
    unsigned short* __restrict__ qkv) {
  __shared__ __align__(16) unsigned char smem[32768];        // As|Bs, Es aliases
  unsigned short* As = (unsigned short*)smem;
  unsigned short* Bs = (unsigned short*)(smem + 16384);
  float4_t acc[4][4];
  for (int i = 0; i < 4; ++i) for (int j = 0; j < 4; ++j)
    acc[i][j] = (float4_t){0.f, 0.f, 0.f, 0.f};
  int lin = blockIdx.y * 24 + blockIdx.x;          // 0..3071, x-fastest
  int swz = (lin & 7) * 384 + (lin >> 3);          // XCD-contiguous bijection
  int bn0 = (swz % 24) * 128, bm0 = (swz / 24) * 128;
  gemm_core(xb, wqkvT, bm0, bn0, 1024, As, Bs, acc);

  int tid = threadIdx.x, w = tid >> 6, lane = tid & 63, quad = lane >> 4, l16 = lane & 15;
  int wm = w >> 1, wn = w & 1;

  // ---- rope in registers (R3 numerics; fcT/fsT float4 loads over r) -------
  for (int i = 0; i < 4; ++i) {
    int t0 = (bm0 + wm * 64 + i * 16 + quad * 4) & 4095;   // r spans t0..t0+3
    for (int j = 0; j < 4; ++j) {
      int gcol = bn0 + wn * 64 + j * 16 + l16;    // wave-uniform branch (16-aligned)
      if (gcol < 2048) {
        int ci = (gcol & 63) >> 1;                // pair index 0..31 (per lane)
        const float4_t c4 = *(const float4_t*)&fcT[(size_t)ci * 4096 + t0];
        const float4_t s4 = *(const float4_t*)&fsT[(size_t)ci * 4096 + t0];
        for (int r = 0; r < 4; ++r) {
          float val = acc[i][j][r];
          float partner = __shfl_xor(val, 1);     // even<->odd channel pair
          float c = c4[r], s = s4[r];             // == fc[t*32+ci], fs[t*32+ci]
          acc[i][j][r] = (gcol & 1) ? fmaf(partner, s, val * c)
                                    : fmaf(-partner, s, val * c);
        }
      }
    }
  }

  // ---- LDS restage + coalesced plain stores -------------------------------
  // Es aliases As/Bs: the barrier guarantees every wave's K-loop ds_reads
  // are complete. After it, each wave's Es slice is private (no more
  // barriers needed — R9-validated intra-wave LDS ordering).
  __syncthreads();
  float* Es = (float*)smem;
  float* slice = &Es[w * 1088];
  for (int i = 0; i < 4; ++i) {
    for (int j = 0; j < 4; ++j)
      for (int r = 0; r < 4; ++r)
        slice[(quad * 4 + r) * 68 + j * 16 + l16] = acc[i][j][r];
    for (int m = 0; m < 2; ++m) {
      int rl = m * 8 + (lane >> 3);               // 0..15 local row
      int cb = (lane & 7) * 8;                    // 8-aligned col base
      const float* rp = &slice[rl * 68 + cb];
      ushort8 outv;
      outv[0] = f2bf(rp[0]); outv[1] = f2bf(rp[1]);
      outv[2] = f2bf(rp[2]); outv[3] = f2bf(rp[3]);
      outv[4] = f2bf(rp[4]); outv[5] = f2bf(rp[5]);
      outv[6] = f2bf(rp[6]); outv[7] = f2bf(rp[7]);
      int grow = bm0 + wm * 64 + i * 16 + rl;     // = b*4096 + t
      int gcol = bn0 + wn * 64 + cb;              // 0..3071, 8-aligned
      *(ushort8*)&qkv[(size_t)grow * 3072 + gcol] = outv;
    }
  }
}

// GEMM2: out = o @ Wo, f32 store into d_out[0 .. 16777216). R16: XCD swizzle.
__global__ __launch_bounds__(256) void gemm2_kernel(const unsigned short* __restrict__ ob,
    const unsigned short* __restrict__ woT, float* __restrict__ outp) {
  __shared__ __align__(16) unsigned short As[128 * 64];
  __shared__ __align__(16) unsigned short Bs[128 * 64];
  float4_t acc[4][4];
  for (int i = 0; i < 4; ++i) for (int j = 0; j < 4; ++j)
    acc[i][j] = (float4_t){0.f, 0.f, 0.f, 0.f};
  int lin = blockIdx.y * 8 + blockIdx.x;           // 0..1023, x-fastest
  int swz = (lin & 7) * 128 + (lin >> 3);          // XCD-contiguous bijection
  int bn0 = (swz & 7) * 128, bm0 = (swz >> 3) * 128;
  gemm_core(ob, woT, bm0, bn0, 1024, As, Bs, acc);
  int tid = threadIdx.x, w = tid >> 6, lane = tid & 63, quad = lane >> 4, l16 = lane & 15;
  int wm = w >> 1, wn = w & 1;
  for (int i = 0; i < 4; ++i)
    for (int j = 0; j < 4; ++j)
      for (int r = 0; r < 4; ++r)
        outp[(size_t)(bm0 + wm * 64 + i * 16 + quad * 4 + r) * 1024 +
             bn0 + wn * 64 + j * 16 + l16] = acc[i][j][r];
}

// ---------------------------------------------------------------------------
// MFMA flash attention. R13 structure (QBLK=128, 512 threads, 8 waves,
// 128-key tiles, ntiles = qt2+1) + R14 T14 async-STAGE split.
// R16: XCD swizzle so the 4 sibling blocks of each (b,h,g) share one XCD's
// L2 (K/V refetch becomes L2-hit).
// Inverse scramble map (R12-validated):
//   q/k row 'row': t = ((row&255)<<4)|h, col = (2g+(row>>8))*64 + hs (+1024 k)
//   v   row 'row': t = g*512+row,        col = 2048 + h*64 + hs
__global__ __launch_bounds__(512) void attn_kernel(const unsigned short* __restrict__ qkv,
    unsigned short* __restrict__ ob) {
  __shared__ __align__(16) unsigned short Ks[128 * 64];      // 1024 swizzled 16B slots
  __shared__ __align__(16) unsigned short VTs[64 * 136];     // [hs][key 0..127], pad->136
  __shared__ __align__(16) unsigned short Ps[8 * 16 * 136];  // per-wave P[16 q][128 k]
  int lin = blockIdx.x;                            // 0..2047
  int bx = (lin & 7) * 256 + (lin >> 3);           // XCD-contiguous bijection
  int qt2 = bx & 3, g = (bx >> 2) & 7, h = (bx >> 5) & 15, b = bx >> 9;
  int tid = threadIdx.x, w = tid >> 6, lane = tid & 63, quad = lane >> 4, l16 = lane & 15;

  const unsigned short* QKb = qkv + ((size_t)b * 4096 + h) * 3072 + g * 128;
  const unsigned short* Vb  = qkv + ((size_t)(b * 4096 + g * 512)) * 3072 + 2048 + h * 64;

  int qrow = qt2 * 128 + w * 16 + l16;
  const unsigned short* Qr = QKb + ((size_t)((qrow & 255) << 4)) * 3072 + (qrow >> 8) * 64;
  bfrag qf0 = *(const bfrag*)&Qr[quad * 8];
  bfrag qf1 = *(const bfrag*)&Qr[32 + quad * 8];

  float4_t acc[4];
#pragma unroll
  for (int i = 0; i < 4; ++i) acc[i] = (float4_t){0.f, 0.f, 0.f, 0.f};
  float m_i[4] = {-1e30f, -1e30f, -1e30f, -1e30f};
  float l_i[4] = {0.f, 0.f, 0.f, 0.f};

  int skey = tid >> 3, sx = tid & 7, ss = sx ^ (skey & 7);   // K staging swizzle
  int kp = tid & 63, hsg = tid >> 6;                          // V staging split (8 hs each)
  unsigned short* Pw = &Ps[w * 2176];                         // 16*136
  int ntiles = qt2 + 1;

  ushort8 kreg0, kreg1, vreg0, vreg1;

  // prologue: load + write tile 0
  {
    int krow0 = skey, krow1 = 64 + skey;
    kreg0 = *(const ushort8*)&QKb[((size_t)((krow0 & 255) << 4)) * 3072 + (krow0 >> 8) * 64 + 1024 + ss * 8];
    kreg1 = *(const ushort8*)&QKb[((size_t)((krow1 & 255) << 4)) * 3072 + (krow1 >> 8) * 64 + 1024 + ss * 8];
    const unsigned short* vp0 = Vb + (size_t)(kp * 2) * 3072 + hsg * 8;
    vreg0 = *(const ushort8*)vp0;
    vreg1 = *(const ushort8*)(vp0 + 3072);
    *(ushort8*)&Ks[(size_t)(tid) * 8]       = kreg0;
    *(ushort8*)&Ks[(size_t)(512 + tid) * 8] = kreg1;
#pragma unroll
    for (int e = 0; e < 8; ++e)
      *(unsigned*)&VTs[(size_t)(hsg * 8 + e) * 136 + kp * 2] =
          (unsigned)vreg0[e] | ((unsigned)vreg1[e] << 16);
  }

  for (int kt = 0; kt < ntiles; ++kt) {
    __syncthreads();   // staged LDS writes for tile kt visible to all waves

    // ---- QK^T (reads Ks) ----
    float4_t s[8];
#pragma unroll
    for (int c = 0; c < 8; ++c) s[c] = (float4_t){0.f, 0.f, 0.f, 0.f};
    {
      int sl0 = l16 * 8 + (quad ^ (l16 & 7));          // hs 0..31, key l16+16c
      int sl1 = l16 * 8 + ((4 + quad) ^ (l16 & 7));    // hs 32..63
#pragma unroll
      for (int c = 0; c < 8; ++c) {
        s[c] = MFMA_BF16(qf0, *(const bfrag*)&Ks[(size_t)(sl0 + 128 * c) * 8], s[c]);
        s[c] = MFMA_BF16(qf1, *(const bfrag*)&Ks[(size_t)(sl1 + 128 * c) * 8], s[c]);
      }
    }

    // ---- issue next tile's global loads (latency hides under softmax+PV) --
    bool more = (kt + 1 < ntiles);
    if (more) {
      int kb = (kt + 1) * 128;
      int krow0 = kb + skey, krow1 = kb + 64 + skey;
      kreg0 = *(const ushort8*)&QKb[((size_t)((krow0 & 255) << 4)) * 3072 + (krow0 >> 8) * 64 + 1024 + ss * 8];
      kreg1 = *(const ushort8*)&QKb[((size_t)((krow1 & 255) << 4)) * 3072 + (krow1 >> 8) * 64 + 1024 + ss * 8];
      const unsigned short* vp0 = Vb + (size_t)(kb + kp * 2) * 3072 + hsg * 8;
      vreg0 = *(const ushort8*)vp0;
      vreg1 = *(const ushort8*)(vp0 + 3072);
    }

    // ---- online softmax ----
    int qa = qt2 * 128 + w * 16 + quad * 4;
    int kb0 = kt * 128 + l16;
#pragma unroll
    for (int r = 0; r < 4; ++r) {
      float vv[8];
#pragma unroll
      for (int c = 0; c < 8; ++c) {
        vv[c] = s[c][r] * 0.125f;
        if (kb0 + 16 * c > qa + r) vv[c] = -1e30f;
      }
      float tm = fmaxf(fmaxf(fmaxf(vv[0], vv[1]), fmaxf(vv[2], vv[3])),
                       fmaxf(fmaxf(vv[4], vv[5]), fmaxf(vv[6], vv[7])));
      tm = fmaxf(tm, __shfl_xor(tm, 1));
      tm = fmaxf(tm, __shfl_xor(tm, 2));
      tm = fmaxf(tm, __shfl_xor(tm, 4));
      tm = fmaxf(tm, __shfl_xor(tm, 8));
      float nm = fmaxf(m_i[r], tm);
      float alpha = __expf(m_i[r] - nm);
      m_i[r] = nm;
      float p[8], rs = 0.f;
#pragma unroll
      for (int c = 0; c < 8; ++c) { p[c] = __expf(vv[c] - nm); rs += p[c]; }
      rs += __shfl_xor(rs, 1);
      rs += __shfl_xor(rs, 2);
      rs += __shfl_xor(rs, 4);
      rs += __shfl_xor(rs, 8);
      l_i[r] = l_i[r] * alpha + rs;
      acc[0][r] *= alpha; acc[1][r] *= alpha; acc[2][r] *= alpha; acc[3][r] *= alpha;
      int pr = (quad * 4 + r) * 136 + l16;
#pragma unroll
      for (int c = 0; c < 8; ++c) Pw[pr + 16 * c] = f2bf(p[c]);
    }
    // No barrier: Pw is this wave's private slice; intra-wave LDS write->read
    // ordering is architectural (lgkmcnt).
    bfrag pf[4];
#pragma unroll
    for (int c = 0; c < 4; ++c)
      pf[c] = *(const bfrag*)&Pw[(size_t)l16 * 136 + 32 * c + quad * 8];
#pragma unroll
    for (int ht = 0; ht < 4; ++ht) {
#pragma unroll
      for (int c = 0; c < 4; ++c) {
        bfrag vf = *(const bfrag*)&VTs[(size_t)(ht * 16 + l16) * 136 + 32 * c + quad * 8];
        acc[ht] = MFMA_BF16(pf[c], vf, acc[ht]);
      }
    }

    __syncthreads();   // all LDS reads of tile kt complete
    if (more) {        // write tile kt+1 (visible after loop-top barrier)
      *(ushort8*)&Ks[(size_t)(tid) * 8]       = kreg0;
      *(ushort8*)&Ks[(size_t)(512 + tid) * 8] = kreg1;
#pragma unroll
      for (int e = 0; e < 8; ++e)
        *(unsigned*)&VTs[(size_t)(hsg * 8 + e) * 136 + kp * 2] =
            (unsigned)vreg0[e] | ((unsigned)vreg1[e] << 16);
    }
  }

  // o_final[b, g*512+gt, h*64+hs]
  int orow = b * 4096 + g * 512 + qt2 * 128 + w * 16 + quad * 4;
#pragma unroll
  for (int ht = 0; ht < 4; ++ht)
#pragma unroll
    for (int r = 0; r < 4; ++r)
      ob[(size_t)(orow + r) * 1024 + h * 64 + ht * 16 + l16] = f2bf(acc[ht][r] / l_i[r]);
}

// ---------------------------------------------------------------------------
// qb/kb/vb: weighted sums over gt (causal_attn on 1x1 == identity => vb pooled)
// 1024 threads/block, 16-way t-split + LDS reduce (validated R8); reads plain
// qkv via the inverse scramble map.
__global__ __launch_bounds__(1024) void pools_kernel(const unsigned short* __restrict__ qkv,
    const float* __restrict__ qp, const float* __restrict__ kp,
    const float* __restrict__ vp, float* __restrict__ outp) {
  __shared__ float red[3][16][64];
  int g = blockIdx.x, h = blockIdx.y, b = blockIdx.z;
  int hs = threadIdx.x & 63, tc = threadIdx.x >> 6;      // 16 chunks x 32 t
  const unsigned short* qb_ = qkv + ((size_t)b * 4096 + h) * 3072 + g * 128 + hs;
  const unsigned short* vb_ = qkv + ((size_t)(b * 4096 + g * 512)) * 3072 + 2048 + h * 64 + hs;
  float aq = 0.f, ak = 0.f, av = 0.f;
  int t0 = tc * 32;
  for (int t = t0; t < t0 + 32; ++t) {
    size_t qoff = ((size_t)((t & 255) << 4)) * 3072 + (t >> 8) * 64;
    aq = fmaf(bf2f(qb_[qoff]), qp[t], aq);
    ak = fmaf(bf2f(qb_[qoff + 1024]), kp[t], ak);
    av = fmaf(bf2f(vb_[(size_t)t * 3072]), vp[t], av);
  }
  red[0][tc][hs] = aq;
  red[1][tc][hs] = ak;
  red[2][tc][hs] = av;
  __syncthreads();
  if (tc < 3) {                                          // tc: 0=q 1=k 2=v
    float a = 0.f;
    for (int c = 0; c < 16; ++c) a += red[tc][c][hs];
    size_t oi = (((size_t)b * 16 + h) * 7 + g) * 64 + hs;
    size_t off = (tc == 0) ? 0 : (tc == 1) ? 28672 : 57344;
    outp[16777216 + off + oi] = a;
  }
}

// ---------------------------------------------------------------------------
extern "C" void kernel_launch(void* const* d_in, const int* in_sizes, int n_in,
                              void* d_out, int out_size, void* d_ws, size_t ws_size,
                              hipStream_t stream) {
  (void)in_sizes; (void)n_in; (void)out_size; (void)ws_size;
  const float* x    = (const float*)d_in[0];
  const float* Wqkv = (const float*)d_in[1];
  const float* Wo   = (const float*)d_in[2];
  const float* qp   = (const float*)d_in[3];
  const float* kp   = (const float*)d_in[4];
  const float* vp   = (const float*)d_in[5];
  const float* fc   = (const float*)d_in[6];
  const float* fs   = (const float*)d_in[7];
  float* outp = (float*)d_out;                     // f32 output (reference dtype)

  char* ws = (char*)d_ws;                          // 142.6 MiB used
  unsigned short* xb    = (unsigned short*)(ws);               // 33.5MB (o aliases it later)
  unsigned short* wqkvT = (unsigned short*)(ws + 33554432);    // 6.3MB
  unsigned short* woT   = (unsigned short*)(ws + 39845888);    // 2.1MB
  unsigned short* qkv   = (unsigned short*)(ws + 41943040);    // 100.7MB [16384][3072]
  unsigned short* ob    = xb;  // safe alias: xb fully consumed by gemm1 before attn writes

  // fcT/fsT scratch lives in d_out[0 .. 512K floats): dead until gemm2, which
  // runs LAST and overwrites it. 32x4096 f32 each.
  float* fcT = outp;
  float* fsT = outp + 131072;

  cvt_kernel<<<8192, 256, 0, stream>>>(x, xb, 2097152);
  transpose_cvt_kernel<<<dim3(96, 32), dim3(32, 8), 0, stream>>>(Wqkv, wqkvT, 1024, 3072);
  transpose_cvt_kernel<<<dim3(32, 32), dim3(32, 8), 0, stream>>>(Wo, woT, 1024, 1024);
  transpose2_f32_kernel<<<dim3(1, 128, 2), dim3(32, 8), 0, stream>>>(fc, fs, fcT, fsT, 4096, 32);
  gemm1_kernel<<<dim3(24, 128), 256, 0, stream>>>(xb, wqkvT, fcT, fsT, qkv);
  attn_kernel<<<2048, 512, 0, stream>>>(qkv, ob);
  pools_kernel<<<dim3(7, 16, 4), 1024, 0, stream>>>(qkv, qp, kp, vp, outp);
  gemm2_kernel<<<dim3(8, 128), 256, 0, stream>>>(ob, woT, outp);
}

// Round 13
// 411.332 us; speedup vs baseline: 1.0721x; 1.0721x over previous
//
#include <hip/hip_runtime.h>

// ---------------------------------------------------------------------------
// CausalSelfAttention2: x@Wqkv -> rope -> 512x block-causal attn -> o@Wo ;
// plus learned time-pooled qb/kb/vb outputs.
// Sizes: B=4 T=4096 C=1024 H=16 G=8 HS=64 GT=512. d_out is FLOAT32.
// R19: GEMM wave decomposition 4x(64x64) -> 8x(32x64) on the same 128x128
// block tile (512 threads). acc 64->32 AGPR, so unified VGPR+AGPR fits 128
// => 4 waves/SIMD (was 2: R18 showed LDS-halving left Occupancy at 20.5%;
// the 92 VGPR + 64 AGPR = 156 > 128 unified-file cap was the real limiter).
// 16 resident waves/CU give the barrier-drain co-resident MFMA work (m114).
// Staging slot/chunk invariants identical (row&7 preserved); epilogues
// re-indexed mechanically (i<2, wm*32). __launch_bounds__(512,4) enforces.
// R16 XCD swizzles, R15 BK=64, R13/R14 attn, pools unchanged.
// ---------------------------------------------------------------------------

typedef float  float4_t  __attribute__((ext_vector_type(4)));
typedef short  bfrag     __attribute__((ext_vector_type(8)));   // 8 bf16
typedef unsigned short ushort8 __attribute__((ext_vector_type(8)));

#define MFMA_BF16(A, B, C) __builtin_amdgcn_mfma_f32_16x16x32_bf16((A), (B), (C), 0, 0, 0)

__device__ __forceinline__ unsigned short f2bf(float f) {
  union { float f; unsigned u; } v; v.f = f;
  return (unsigned short)((v.u + 0x7FFFu + ((v.u >> 16) & 1u)) >> 16);   // RNE
}
__device__ __forceinline__ float bf2f(unsigned short h) {
  union { unsigned u; float f; } v; v.u = ((unsigned)h) << 16; return v.f;
}
// async global->LDS, 16B per lane; LDS dest = wave-uniform base + lane*16
__device__ __forceinline__ void async16(const void* g, void* l) {
  __builtin_amdgcn_global_load_lds(
      (const __attribute__((address_space(1))) unsigned int*)(unsigned long long)g,
      (__attribute__((address_space(3))) unsigned int*)(unsigned long long)l,
      16, 0, 0);
}

// ---------------------------------------------------------------------------
// f32 -> bf16 convert (8 elems/thread)
__global__ __launch_bounds__(256) void cvt_kernel(const float* __restrict__ in,
                                                  unsigned short* __restrict__ out, int n8) {
  int i = blockIdx.x * 256 + threadIdx.x;
  if (i >= n8) return;
  const float4_t* p = (const float4_t*)in + (size_t)i * 2;
  float4_t a = p[0], c = p[1];
  ushort8 r;
  r[0] = f2bf(a[0]); r[1] = f2bf(a[1]); r[2] = f2bf(a[2]); r[3] = f2bf(a[3]);
  r[4] = f2bf(c[0]); r[5] = f2bf(c[1]); r[6] = f2bf(c[2]); r[7] = f2bf(c[3]);
  *((ushort8*)out + i) = r;
}

// out[n][k] = bf16(in[k][n]);  in is [R,C] f32, out is [C,R] bf16
__global__ void transpose_cvt_kernel(const float* __restrict__ in,
                                     unsigned short* __restrict__ out, int R, int C) {
  __shared__ float t[32][33];
  int bc = blockIdx.x * 32, br = blockIdx.y * 32;
  int x = threadIdx.x, y = threadIdx.y;
  for (int i = 0; i < 32; i += 8) t[y + i][x] = in[(size_t)(br + y + i) * C + bc + x];
  __syncthreads();
  for (int i = 0; i < 32; i += 8) out[(size_t)(bc + y + i) * R + br + x] = f2bf(t[x][y + i]);
}

// out[n][k] = in[k][n]; f32 transpose of TWO tables (z selects), R=4096 C=32
__global__ void transpose2_f32_kernel(const float* __restrict__ a,
                                      const float* __restrict__ b,
                                      float* __restrict__ oa, float* __restrict__ ob_,
                                      int R, int C) {
  const float* in = blockIdx.z ? b : a;
  float* out = blockIdx.z ? ob_ : oa;
  __shared__ float t[32][33];
  int bc = blockIdx.x * 32, br = blockIdx.y * 32;
  int x = threadIdx.x, y = threadIdx.y;
  for (int i = 0; i < 32; i += 8) t[y + i][x] = in[(size_t)(br + y + i) * C + bc + x];
  __syncthreads();
  for (int i = 0; i < 32; i += 8) out[(size_t)(bc + y + i) * R + br + x] = t[x][y + i];
}

// ---------------------------------------------------------------------------
// Shared GEMM core: C128x128 tile, BK=64, 8 waves (each 32x64 = 2x4 frags).
// A [M,K] bf16 row-major, BT [N,K] bf16 row-major. 512 threads.
// LDS tile 128x64: slot s (16B) holds row s>>3, chunk (s&7)^((s>>3)&7).
// Writer (512 thr): thread (r=tid>>3 in [0,64), x=tid&7), row-group c<2:
// row c*64+r, source chunk x^(r&7), dest slot c*512+tid. row&7==r&7 ✓.
__device__ __forceinline__ void gemm_core(const unsigned short* __restrict__ A,
                                          const unsigned short* __restrict__ BT,
                                          int bm0, int bn0, int K,
                                          unsigned short* As, unsigned short* Bs,
                                          float4_t acc[2][4]) {
  int tid = threadIdx.x, w = tid >> 6;
  int lane = tid & 63, quad = lane >> 4, l16 = lane & 15;
  int wm = w >> 1, wn = w & 1;                     // 4x2 wave grid, 32x64 each
  int r = tid >> 3, x = tid & 7;
  int sc = (x ^ (r & 7)) * 8;                      // swizzled source col
  for (int k0 = 0; k0 < K; k0 += 64) {
    __syncthreads();
#pragma unroll
    for (int c = 0; c < 2; ++c) {
      async16(&A [(size_t)(bm0 + c * 64 + r) * K + k0 + sc], &As[(size_t)(c * 512 + tid) * 8]);
      async16(&BT[(size_t)(bn0 + c * 64 + r) * K + k0 + sc], &Bs[(size_t)(c * 512 + tid) * 8]);
    }
    __syncthreads();
#pragma unroll
    for (int ks = 0; ks < 2; ++ks) {
      bfrag af[2], bf_[4];
#pragma unroll
      for (int i = 0; i < 2; ++i) {
        int rm = wm * 32 + i * 16 + l16;
        af[i]  = *(const bfrag*)&As[(size_t)(rm * 8 + ((ks * 4 + quad) ^ (rm & 7))) * 8];
      }
#pragma unroll
      for (int j = 0; j < 4; ++j) {
        int rn = wn * 64 + j * 16 + l16;
        bf_[j] = *(const bfrag*)&Bs[(size_t)(rn * 8 + ((ks * 4 + quad) ^ (rn & 7))) * 8];
      }
#pragma unroll
      for (int i = 0; i < 2; ++i)
#pragma unroll
        for (int j = 0; j < 4; ++j)
          acc[i][j] = MFMA_BF16(af[i], bf_[j], acc[i][j]);
    }
  }
}

// GEMM1: qkv = rope(x @ Wqkv) stored PLAIN row-major [16384][3072].
// R19: 512 threads, 8 waves x 32x64; Es (8x1088 f32 = 34.8KB) aliases As/Bs.
__global__ __launch_bounds__(512, 4) void gemm1_kernel(const unsigned short* __restrict__ xb,
    const unsigned short* __restrict__ wqkvT,
    const float* __restrict__ fcT, const float* __restrict__ fsT,
    unsigned short* __restrict__ qkv) {
  __shared__ __align__(16) unsigned char smem[34816];        // max(As|Bs 32K, Es 34.8K)
  unsigned short* As = (unsigned short*)smem;
  unsigned short* Bs = (unsigned short*)(smem + 16384);
  float4_t acc[2][4];
  for (int i = 0; i < 2; ++i) for (int j = 0; j < 4; ++j)
    acc[i][j] = (float4_t){0.f, 0.f, 0.f, 0.f};
  int lin = blockIdx.y * 24 + blockIdx.x;          // 0..3071, x-fastest
  int swz = (lin & 7) * 384 + (lin >> 3);          // XCD-contiguous bijection
  int bn0 = (swz % 24) * 128, bm0 = (swz / 24) * 128;
  gemm_core(xb, wqkvT, bm0, bn0, 1024, As, Bs, acc);

  int tid = threadIdx.x, w = tid >> 6, lane = tid & 63, quad = lane >> 4, l16 = lane & 15;
  int wm = w >> 1, wn = w & 1;

  // ---- rope in registers (R3 numerics; fcT/fsT float4 loads over r) -------
  for (int i = 0; i < 2; ++i) {
    int t0 = (bm0 + wm * 32 + i * 16 + quad * 4) & 4095;   // r spans t0..t0+3
    for (int j = 0; j < 4; ++j) {
      int gcol = bn0 + wn * 64 + j * 16 + l16;    // wave-uniform branch (16-aligned)
      if (gcol < 2048) {
        int ci = (gcol & 63) >> 1;                // pair index 0..31 (per lane)
        const float4_t c4 = *(const float4_t*)&fcT[(size_t)ci * 4096 + t0];
        const float4_t s4 = *(const float4_t*)&fsT[(size_t)ci * 4096 + t0];
        for (int r = 0; r < 4; ++r) {
          float val = acc[i][j][r];
          float partner = __shfl_xor(val, 1);     // even<->odd channel pair
          float c = c4[r], s = s4[r];             // == fc[t*32+ci], fs[t*32+ci]
          acc[i][j][r] = (gcol & 1) ? fmaf(partner, s, val * c)
                                    : fmaf(-partner, s, val * c);
        }
      }
    }
  }

  // ---- LDS restage + coalesced plain stores -------------------------------
  // Es aliases As/Bs: barrier ensures all K-loop ds_reads done; after it each
  // wave's Es slice is private (R9-validated intra-wave LDS ordering).
  __syncthreads();
  float* Es = (float*)smem;
  float* slice = &Es[w * 1088];
  for (int i = 0; i < 2; ++i) {
    for (int j = 0; j < 4; ++j)
      for (int r = 0; r < 4; ++r)
        slice[(quad * 4 + r) * 68 + j * 16 + l16] = acc[i][j][r];
    for (int m = 0; m < 2; ++m) {
      int rl = m * 8 + (lane >> 3);               // 0..15 local row
      int cb = (lane & 7) * 8;                    // 8-aligned col base
      const float* rp = &slice[rl * 68 + cb];
      ushort8 outv;
      outv[0] = f2bf(rp[0]); outv[1] = f2bf(rp[1]);
      outv[2] = f2bf(rp[2]); outv[3] = f2bf(rp[3]);
      outv[4] = f2bf(rp[4]); outv[5] = f2bf(rp[5]);
      outv[6] = f2bf(rp[6]); outv[7] = f2bf(rp[7]);
      int grow = bm0 + wm * 32 + i * 16 + rl;     // = b*4096 + t
      int gcol = bn0 + wn * 64 + cb;              // 0..3071, 8-aligned
      *(ushort8*)&qkv[(size_t)grow * 3072 + gcol] = outv;
    }
  }
}

// GEMM2: out = o @ Wo, f32 store into d_out[0 .. 16777216). R19: 512 thr.
__global__ __launch_bounds__(512, 4) void gemm2_kernel(const unsigned short* __restrict__ ob,
    const unsigned short* __restrict__ woT, float* __restrict__ outp) {
  __shared__ __align__(16) unsigned short As[128 * 64];
  __shared__ __align__(16) unsigned short Bs[128 * 64];
  float4_t acc[2][4];
  for (int i = 0; i < 2; ++i) for (int j = 0; j < 4; ++j)
    acc[i][j] = (float4_t){0.f, 0.f, 0.f, 0.f};
  int lin = blockIdx.y * 8 + blockIdx.x;           // 0..1023, x-fastest
  int swz = (lin & 7) * 128 + (lin >> 3);          // XCD-contiguous bijection
  int bn0 = (swz & 7) * 128, bm0 = (swz >> 3) * 128;
  gemm_core(ob, woT, bm0, bn0, 1024, As, Bs, acc);
  int tid = threadIdx.x, w = tid >> 6, lane = tid & 63, quad = lane >> 4, l16 = lane & 15;
  int wm = w >> 1, wn = w & 1;
  for (int i = 0; i < 2; ++i)
    for (int j = 0; j < 4; ++j)
      for (int r = 0; r < 4; ++r)
        outp[(size_t)(bm0 + wm * 32 + i * 16 + quad * 4 + r) * 1024 +
             bn0 + wn * 64 + j * 16 + l16] = acc[i][j][r];
}

// ---------------------------------------------------------------------------
// MFMA flash attention. R13 structure (QBLK=128, 512 threads, 8 waves,
// 128-key tiles, ntiles = qt2+1) + R14 T14 async-STAGE split.
// R16: XCD swizzle so the 4 sibling blocks of each (b,h,g) share one XCD's
// L2 (K/V refetch becomes L2-hit).
// Inverse scramble map (R12-validated):
//   q/k row 'row': t = ((row&255)<<4)|h, col = (2g+(row>>8))*64 + hs (+1024 k)
//   v   row 'row': t = g*512+row,        col = 2048 + h*64 + hs
__global__ __launch_bounds__(512) void attn_kernel(const unsigned short* __restrict__ qkv,
    unsigned short* __restrict__ ob) {
  __shared__ __align__(16) unsigned short Ks[128 * 64];      // 1024 swizzled 16B slots
  __shared__ __align__(16) unsigned short VTs[64 * 136];     // [hs][key 0..127], pad->136
  __shared__ __align__(16) unsigned short Ps[8 * 16 * 136];  // per-wave P[16 q][128 k]
  int lin = blockIdx.x;                            // 0..2047
  int bx = (lin & 7) * 256 + (lin >> 3);           // XCD-contiguous bijection
  int qt2 = bx & 3, g = (bx >> 2) & 7, h = (bx >> 5) & 15, b = bx >> 9;
  int tid = threadIdx.x, w = tid >> 6, lane = tid & 63, quad = lane >> 4, l16 = lane & 15;

  const unsigned short* QKb = qkv + ((size_t)b * 4096 + h) * 3072 + g * 128;
  const unsigned short* Vb  = qkv + ((size_t)(b * 4096 + g * 512)) * 3072 + 2048 + h * 64;

  int qrow = qt2 * 128 + w * 16 + l16;
  const unsigned short* Qr = QKb + ((size_t)((qrow & 255) << 4)) * 3072 + (qrow >> 8) * 64;
  bfrag qf0 = *(const bfrag*)&Qr[quad * 8];
  bfrag qf1 = *(const bfrag*)&Qr[32 + quad * 8];

  float4_t acc[4];
#pragma unroll
  for (int i = 0; i < 4; ++i) acc[i] = (float4_t){0.f, 0.f, 0.f, 0.f};
  float m_i[4] = {-1e30f, -1e30f, -1e30f, -1e30f};
  float l_i[4] = {0.f, 0.f, 0.f, 0.f};

  int skey = tid >> 3, sx = tid & 7, ss = sx ^ (skey & 7);   // K staging swizzle
  int kp = tid & 63, hsg = tid >> 6;                          // V staging split (8 hs each)
  unsigned short* Pw = &Ps[w * 2176];                         // 16*136
  int ntiles = qt2 + 1;

  ushort8 kreg0, kreg1, vreg0, vreg1;

  // prologue: load + write tile 0
  {
    int krow0 = skey, krow1 = 64 + skey;
    kreg0 = *(const ushort8*)&QKb[((size_t)((krow0 & 255) << 4)) * 3072 + (krow0 >> 8) * 64 + 1024 + ss * 8];
    kreg1 = *(const ushort8*)&QKb[((size_t)((krow1 & 255) << 4)) * 3072 + (krow1 >> 8) * 64 + 1024 + ss * 8];
    const unsigned short* vp0 = Vb + (size_t)(kp * 2) * 3072 + hsg * 8;
    vreg0 = *(const ushort8*)vp0;
    vreg1 = *(const ushort8*)(vp0 + 3072);
    *(ushort8*)&Ks[(size_t)(tid) * 8]       = kreg0;
    *(ushort8*)&Ks[(size_t)(512 + tid) * 8] = kreg1;
#pragma unroll
    for (int e = 0; e < 8; ++e)
      *(unsigned*)&VTs[(size_t)(hsg * 8 + e) * 136 + kp * 2] =
          (unsigned)vreg0[e] | ((unsigned)vreg1[e] << 16);
  }

  for (int kt = 0; kt < ntiles; ++kt) {
    __syncthreads();   // staged LDS writes for tile kt visible to all waves

    // ---- QK^T (reads Ks) ----
    float4_t s[8];
#pragma unroll
    for (int c = 0; c < 8; ++c) s[c] = (float4_t){0.f, 0.f, 0.f, 0.f};
    {
      int sl0 = l16 * 8 + (quad ^ (l16 & 7));          // hs 0..31, key l16+16c
      int sl1 = l16 * 8 + ((4 + quad) ^ (l16 & 7));    // hs 32..63
#pragma unroll
      for (int c = 0; c < 8; ++c) {
        s[c] = MFMA_BF16(qf0, *(const bfrag*)&Ks[(size_t)(sl0 + 128 * c) * 8], s[c]);
        s[c] = MFMA_BF16(qf1, *(const bfrag*)&Ks[(size_t)(sl1 + 128 * c) * 8], s[c]);
      }
    }

    // ---- issue next tile's global loads (latency hides under softmax+PV) --
    bool more = (kt + 1 < ntiles);
    if (more) {
      int kb = (kt + 1) * 128;
      int krow0 = kb + skey, krow1 = kb + 64 + skey;
      kreg0 = *(const ushort8*)&QKb[((size_t)((krow0 & 255) << 4)) * 3072 + (krow0 >> 8) * 64 + 1024 + ss * 8];
      kreg1 = *(const ushort8*)&QKb[((size_t)((krow1 & 255) << 4)) * 3072 + (krow1 >> 8) * 64 + 1024 + ss * 8];
      const unsigned short* vp0 = Vb + (size_t)(kb + kp * 2) * 3072 + hsg * 8;
      vreg0 = *(const ushort8*)vp0;
      vreg1 = *(const ushort8*)(vp0 + 3072);
    }

    // ---- online softmax ----
    int qa = qt2 * 128 + w * 16 + quad * 4;
    int kb0 = kt * 128 + l16;
#pragma unroll
    for (int r = 0; r < 4; ++r) {
      float vv[8];
#pragma unroll
      for (int c = 0; c < 8; ++c) {
        vv[c] = s[c][r] * 0.125f;
        if (kb0 + 16 * c > qa + r) vv[c] = -1e30f;
      }
      float tm = fmaxf(fmaxf(fmaxf(vv[0], vv[1]), fmaxf(vv[2], vv[3])),
                       fmaxf(fmaxf(vv[4], vv[5]), fmaxf(vv[6], vv[7])));
      tm = fmaxf(tm, __shfl_xor(tm, 1));
      tm = fmaxf(tm, __shfl_xor(tm, 2));
      tm = fmaxf(tm, __shfl_xor(tm, 4));
      tm = fmaxf(tm, __shfl_xor(tm, 8));
      float nm = fmaxf(m_i[r], tm);
      float alpha = __expf(m_i[r] - nm);
      m_i[r] = nm;
      float p[8], rs = 0.f;
#pragma unroll
      for (int c = 0; c < 8; ++c) { p[c] = __expf(vv[c] - nm); rs += p[c]; }
      rs += __shfl_xor(rs, 1);
      rs += __shfl_xor(rs, 2);
      rs += __shfl_xor(rs, 4);
      rs += __shfl_xor(rs, 8);
      l_i[r] = l_i[r] * alpha + rs;
      acc[0][r] *= alpha; acc[1][r] *= alpha; acc[2][r] *= alpha; acc[3][r] *= alpha;
      int pr = (quad * 4 + r) * 136 + l16;
#pragma unroll
      for (int c = 0; c < 8; ++c) Pw[pr + 16 * c] = f2bf(p[c]);
    }
    // No barrier: Pw is this wave's private slice; intra-wave LDS write->read
    // ordering is architectural (lgkmcnt).
    bfrag pf[4];
#pragma unroll
    for (int c = 0; c < 4; ++c)
      pf[c] = *(const bfrag*)&Pw[(size_t)l16 * 136 + 32 * c + quad * 8];
#pragma unroll
    for (int ht = 0; ht < 4; ++ht) {
#pragma unroll
      for (int c = 0; c < 4; ++c) {
        bfrag vf = *(const bfrag*)&VTs[(size_t)(ht * 16 + l16) * 136 + 32 * c + quad * 8];
        acc[ht] = MFMA_BF16(pf[c], vf, acc[ht]);
      }
    }

    __syncthreads();   // all LDS reads of tile kt complete
    if (more) {        // write tile kt+1 (visible after loop-top barrier)
      *(ushort8*)&Ks[(size_t)(tid) * 8]       = kreg0;
      *(ushort8*)&Ks[(size_t)(512 + tid) * 8] = kreg1;
#pragma unroll
      for (int e = 0; e < 8; ++e)
        *(unsigned*)&VTs[(size_t)(hsg * 8 + e) * 136 + kp * 2] =
            (unsigned)vreg0[e] | ((unsigned)vreg1[e] << 16);
    }
  }

  // o_final[b, g*512+gt, h*64+hs]
  int orow = b * 4096 + g * 512 + qt2 * 128 + w * 16 + quad * 4;
#pragma unroll
  for (int ht = 0; ht < 4; ++ht)
#pragma unroll
    for (int r = 0; r < 4; ++r)
      ob[(size_t)(orow + r) * 1024 + h * 64 + ht * 16 + l16] = f2bf(acc[ht][r] / l_i[r]);
}

// ---------------------------------------------------------------------------
// qb/kb/vb: weighted sums over gt (causal_attn on 1x1 == identity => vb pooled)
// 1024 threads/block, 16-way t-split + LDS reduce (validated R8); reads plain
// qkv via the inverse scramble map.
__global__ __launch_bounds__(1024) void pools_kernel(const unsigned short* __restrict__ qkv,
    const float* __restrict__ qp, const float* __restrict__ kp,
    const float* __restrict__ vp, float* __restrict__ outp) {
  __shared__ float red[3][16][64];
  int g = blockIdx.x, h = blockIdx.y, b = blockIdx.z;
  int hs = threadIdx.x & 63, tc = threadIdx.x >> 6;      // 16 chunks x 32 t
  const unsigned short* qb_ = qkv + ((size_t)b * 4096 + h) * 3072 + g * 128 + hs;
  const unsigned short* vb_ = qkv + ((size_t)(b * 4096 + g * 512)) * 3072 + 2048 + h * 64 + hs;
  float aq = 0.f, ak = 0.f, av = 0.f;
  int t0 = tc * 32;
  for (int t = t0; t < t0 + 32; ++t) {
    size_t qoff = ((size_t)((t & 255) << 4)) * 3072 + (t >> 8) * 64;
    aq = fmaf(bf2f(qb_[qoff]), qp[t], aq);
    ak = fmaf(bf2f(qb_[qoff + 1024]), kp[t], ak);
    av = fmaf(bf2f(vb_[(size_t)t * 3072]), vp[t], av);
  }
  red[0][tc][hs] = aq;
  red[1][tc][hs] = ak;
  red[2][tc][hs] = av;
  __syncthreads();
  if (tc < 3) {                                          // tc: 0=q 1=k 2=v
    float a = 0.f;
    for (int c = 0; c < 16; ++c) a += red[tc][c][hs];
    size_t oi = (((size_t)b * 16 + h) * 7 + g) * 64 + hs;
    size_t off = (tc == 0) ? 0 : (tc == 1) ? 28672 : 57344;
    outp[16777216 + off + oi] = a;
  }
}

// ---------------------------------------------------------------------------
extern "C" void kernel_launch(void* const* d_in, const int* in_sizes, int n_in,
                              void* d_out, int out_size, void* d_ws, size_t ws_size,
                              hipStream_t stream) {
  (void)in_sizes; (void)n_in; (void)out_size; (void)ws_size;
  const float* x    = (const float*)d_in[0];
  const float* Wqkv = (const float*)d_in[1];
  const float* Wo   = (const float*)d_in[2];
  const float* qp   = (const float*)d_in[3];
  const float* kp   = (const float*)d_in[4];
  const float* vp   = (const float*)d_in[5];
  const float* fc   = (const float*)d_in[6];
  const float* fs   = (const float*)d_in[7];
  float* outp = (float*)d_out;                     // f32 output (reference dtype)

  char* ws = (char*)d_ws;                          // 142.6 MiB used
  unsigned short* xb    = (unsigned short*)(ws);               // 33.5MB (o aliases it later)
  unsigned short* wqkvT = (unsigned short*)(ws + 33554432);    // 6.3MB
  unsigned short* woT   = (unsigned short*)(ws + 39845888);    // 2.1MB
  unsigned short* qkv   = (unsigned short*)(ws + 41943040);    // 100.7MB [16384][3072]
  unsigned short* ob    = xb;  // safe alias: xb fully consumed by gemm1 before attn writes

  // fcT/fsT scratch lives in d_out[0 .. 512K floats): dead until gemm2, which
  // runs LAST and overwrites it. 32x4096 f32 each.
  float* fcT = outp;
  float* fsT = outp + 131072;

  cvt_kernel<<<8192, 256, 0, stream>>>(x, xb, 2097152);
  transpose_cvt_kernel<<<dim3(96, 32), dim3(32, 8), 0, stream>>>(Wqkv, wqkvT, 1024, 3072);
  transpose_cvt_kernel<<<dim3(32, 32), dim3(32, 8), 0, stream>>>(Wo, woT, 1024, 1024);
  transpose2_f32_kernel<<<dim3(1, 128, 2), dim3(32, 8), 0, stream>>>(fc, fs, fcT, fsT, 4096, 32);
  gemm1_kernel<<<dim3(24, 128), 512, 0, stream>>>(xb, wqkvT, fcT, fsT, qkv);
  attn_kernel<<<2048, 512, 0, stream>>>(qkv, ob);
  pools_kernel<<<dim3(7, 16, 4), 1024, 0, stream>>>(qkv, qp, kp, vp, outp);
  gemm2_kernel<<<dim3(8, 128), 512, 0, stream>>>(ob, woT, outp);
}